// Round 6
// baseline (6517.098 us; speedup 1.0000x reference)
//
#include <hip/hip_runtime.h>
#include <math.h>

// Decoder_82231443849250: persistent-kernel recurrent MLP decoder. Round 6.
// 8 batch-groups (32 rows) x 32 WGs (32-col slices); g = bid&7 (XCD-aligned
// under %8 round-robin; correctness of data exchange via shared XCD L2 was
// validated in rounds 4/5).
// Barrier v3: per-WG 64B-spaced slot counters. Arrival = ONE uncontended
// relaxed agent-scope fetch_add on own slot (lands at coherence point).
// Poll = wave 0, per-lane global_load sc0 sc1 of all 32 slots in ONE vector
// load + __all(v>=nbar). Acquire = buffer_inv sc0 (L1-only).
// LN1/LN2 fused into consumer GEMMs via LDS A-staging (5 -> 3 barriers/step).
// All activations bf16. W2/Wa1 pre-converted to bf16 workspace.

#define NB 256
#define NS 128
#define NH 1024
#define NJ 12
#define NPIN 139
#define NPD 42
#define WPG 32
#define BROW 32
#define AS 1032  // albuf row stride in ushorts (stride 2064B -> bank-tiling ok)

typedef __attribute__((ext_vector_type(8))) short short8;
typedef __attribute__((ext_vector_type(4))) float f32x4;
typedef __attribute__((ext_vector_type(4))) unsigned short u16x4;

struct Params {
  const float* z; const float* obs; const float* W1; const float* b1;
  const float* g1; const float* be1; const float* W2; const float* b2;
  const float* g2; const float* be2; const float* Wa1; const float* ba1;
  const float* Wa2; const float* ba2; const float* Wo; const float* bo;
  const float* Wv; const float* bv; const float* alog; const float* fkW;
  const float* fkb; const float* pmean; const float* pstd; const float* jlo;
  const float* jhi; const float* ddp;
  float* out_gmu; float* out_joint; float* out_act; float* out_ls;
  float* zc;
  unsigned short* y1b; unsigned short* y2b; unsigned short* t1;
  unsigned short* w2b; unsigned short* wa1b; unsigned short* wa2b; unsigned short* wexb;
  unsigned int* gcnt; unsigned int* slots;
};

__device__ __forceinline__ unsigned short f2bf(float x) {
  union { float f; unsigned u; } v; v.f = x;
  unsigned r = v.u + 0x7FFFu + ((v.u >> 16) & 1u);
  return (unsigned short)(r >> 16);
}
__device__ __forceinline__ float bf2f(unsigned short x) {
  union { unsigned u; float f; } v; v.u = ((unsigned)x) << 16;
  return v.f;
}

__device__ __forceinline__ f32x4 dot1024(const unsigned short* a, const unsigned short* b) {
  const short8* ap = (const short8*)a;
  const short8* bp = (const short8*)b;
  f32x4 acc0 = {0.f, 0.f, 0.f, 0.f};
  f32x4 acc1 = {0.f, 0.f, 0.f, 0.f};
#pragma unroll 4
  for (int k8 = 0; k8 < 128; k8 += 8) {
    acc0 = __builtin_amdgcn_mfma_f32_16x16x32_bf16(ap[k8], bp[k8], acc0, 0, 0, 0);
    acc1 = __builtin_amdgcn_mfma_f32_16x16x32_bf16(ap[k8 + 4], bp[k8 + 4], acc1, 0, 0, 0);
  }
  return acc0 + acc1;
}

// ---- one-time global barrier (cross-XCD safe): full fences, used once.
__device__ __forceinline__ void gbar(unsigned int* c, unsigned int target) {
  __threadfence();
  __syncthreads();
  if (threadIdx.x == 0) {
    __hip_atomic_fetch_add(c, 1u, __ATOMIC_RELEASE, __HIP_MEMORY_SCOPE_AGENT);
    unsigned long long t0 = __builtin_amdgcn_s_memrealtime();
    while (__hip_atomic_load(c, __ATOMIC_ACQUIRE, __HIP_MEMORY_SCOPE_AGENT) < target) {
      __builtin_amdgcn_s_sleep(16);
      if (__builtin_amdgcn_s_memrealtime() - t0 > (1ull << 25)) break;  // bail, never hang
    }
  }
  __syncthreads();
  __threadfence();
}

// ---- XCD-local slot barrier (see header). sg = this group's 32-slot base
// (slots 64B apart). Each WG's slot is a monotonic per-barrier counter.
__device__ __forceinline__ void xbar2(unsigned int* sg, int w, unsigned target,
                                      int wave, int lane) {
  asm volatile("s_waitcnt vmcnt(0)" ::: "memory");
  __syncthreads();
  if (wave == 0) {
    if (lane == 0)
      __hip_atomic_fetch_add(sg + (size_t)w * 16, 1u, __ATOMIC_RELAXED,
                             __HIP_MEMORY_SCOPE_AGENT);
    const unsigned int* myslot = sg + (size_t)(lane & 31) * 16;
    unsigned long long t0 = __builtin_amdgcn_s_memrealtime();
    for (;;) {
      unsigned v;
      asm volatile("global_load_dword %0, %1, off sc0 sc1\n\t"
                   "s_waitcnt vmcnt(0)"
                   : "=v"(v) : "v"(myslot) : "memory");
      if (__all(v >= target)) break;
      __builtin_amdgcn_s_sleep(1);
      if (__builtin_amdgcn_s_memrealtime() - t0 > (1ull << 23)) break;  // bail, never hang
    }
  }
  __syncthreads();
  asm volatile("buffer_inv sc0" ::: "memory");  // invalidate vector L1 only
}

__global__ __launch_bounds__(256, 2) void decoder_persistent(Params p) {
  __shared__ unsigned short albuf[BROW * AS];         // 66 KB: normalized A (bf16)
  __shared__ float pj_l[BROW * NJ];
  __shared__ float pdq_l[BROW * NJ];
  __shared__ float aex[BROW * 16];
  __shared__ float alpha_l[NJ], jm_l[NJ], jri_l[NJ], lo_l[NJ], hi_l[NJ], ddp_l[NJ], ba2_l[NJ];
  __shared__ float pm_l[NPD], psi_l[NPD], bv_l[NPD], bo_l[4];

  const int tid = threadIdx.x;
  const int bid = blockIdx.x;
  const int g = bid & 7;        // group == XCD under default %8 round-robin
  const int w = bid >> 3;       // WG-in-group: owns cols [w*32, w*32+32)
  const int b0 = g * BROW;
  const int n0 = w * 32;
  const int wave = tid >> 6;
  const int lane = tid & 63;

  unsigned int* sg = p.slots + (size_t)g * 512;  // 32 slots x 16 dwords (64B)

  unsigned short* y1bg = p.y1b + (size_t)g * BROW * NH;
  unsigned short* y2bg = p.y2b + (size_t)g * BROW * NH;
  unsigned short* t1g = p.t1 + (size_t)g * BROW * NH;

  // ---------------- P0: one-time setup ----------------
  if (tid < NJ) {
    alpha_l[tid] = 1.f / (1.f + expf(-p.alog[tid]));
    float lo = p.jlo[tid], hi = p.jhi[tid];
    jm_l[tid] = 0.5f * (hi + lo);
    jri_l[tid] = 2.f / (hi - lo);
    lo_l[tid] = lo; hi_l[tid] = hi;
    ddp_l[tid] = p.ddp[tid]; ba2_l[tid] = p.ba2[tid];
  }
  if (tid < NPD) { pm_l[tid] = p.pmean[tid]; psi_l[tid] = 1.f / p.pstd[tid]; bv_l[tid] = p.bv[tid]; }
  if (tid < 3) bo_l[tid] = p.bo[tid];
  for (int idx = tid; idx < BROW * NJ; idx += 256) { pj_l[idx] = p.ddp[idx % NJ]; pdq_l[idx] = 0.f; }
  // W2, Wa1 -> bf16 ws: rows n0+g*4..+3 over all (g,w) cover 1024 rows once
  for (int idx = tid; idx < 4 * NH; idx += 256) {
    int r = idx >> 10, k = idx & (NH - 1);
    int row = n0 + g * 4 + r;
    p.w2b[(size_t)row * NH + k] = f2bf(p.W2[(size_t)row * NH + k]);
    p.wa1b[(size_t)row * NH + k] = f2bf(p.Wa1[(size_t)row * NH + k]);
  }
  {  // zc = z @ W1z^T + b1 (constant across steps, f32)
    int r = tid >> 3, cq = tid & 7;
    int nb = n0 + cq * 4;
    const float* zr = p.z + (size_t)(b0 + r) * 64;
    const float* w1r = p.W1 + (size_t)nb * NPIN + 75;
    float a0 = p.b1[nb], a1 = p.b1[nb + 1], a2 = p.b1[nb + 2], a3 = p.b1[nb + 3];
    for (int k = 0; k < 64; ++k) {
      float zv = zr[k];
      a0 += zv * w1r[k]; a1 += zv * w1r[NPIN + k];
      a2 += zv * w1r[2 * NPIN + k]; a3 += zv * w1r[3 * NPIN + k];
    }
    f32x4 st = {a0, a1, a2, a3};
    *(f32x4*)(p.zc + (size_t)(b0 + r) * NH + nb) = st;
  }
  if (bid == 0) {  // Wa2 padded to 16 rows
    for (int idx = tid; idx < 16 * NH; idx += 256) {
      int r = idx >> 10, k = idx & (NH - 1);
      p.wa2b[idx] = (r < NJ) ? f2bf(p.Wa2[(size_t)r * NH + k]) : (unsigned short)0;
    }
  }
  if (bid == 1) {  // [Wo(3); Wv(42); zeros(3)] padded to 48 rows
    for (int idx = tid; idx < 48 * NH; idx += 256) {
      int r = idx >> 10, k = idx & (NH - 1);
      unsigned short v = 0;
      if (r < 3) v = f2bf(p.Wo[(size_t)r * NH + k]);
      else if (r < 45) v = f2bf(p.Wv[(size_t)(r - 3) * NH + k]);
      p.wexb[idx] = v;
    }
  }
  gbar(p.gcnt, 256u);  // one-time cross-XCD barrier (weight conversions)

  // ---------------- phase lambdas ----------------
  // Fused LN: read y (bf16) rows, stats in f32, normalize(+gamma/beta)+relu
  // -> albuf (bf16). 8 threads per row, 128 cols each. Raw pass stages to
  // LDS so we don't re-read global (and keep registers low).
  auto ln_stage = [&](const unsigned short* yb, const float* gamma, const float* beta) {
    const int r = tid >> 3, c0 = (tid & 7) * 128;
    const short8* yp = (const short8*)(yb + (size_t)r * NH + c0);
    short8* lp = (short8*)&albuf[r * AS + c0];
    float s = 0.f, q = 0.f;
#pragma unroll
    for (int i = 0; i < 16; ++i) {
      short8 v = yp[i];
      lp[i] = v;
#pragma unroll
      for (int j = 0; j < 8; ++j) {
        float x = bf2f((unsigned short)v[j]);
        s += x; q += x * x;
      }
    }
#pragma unroll
    for (int off = 4; off; off >>= 1) {
      s += __shfl_down(s, off, 8);
      q += __shfl_down(q, off, 8);
    }
    s = __shfl(s, 0, 8);
    q = __shfl(q, 0, 8);
    float m = s * (1.0f / 1024.0f);
    float rs = rsqrtf(q * (1.0f / 1024.0f) - m * m + 1e-5f);
#pragma unroll
    for (int i = 0; i < 16; ++i) {
      short8 v = lp[i];
      short8 o;
#pragma unroll
      for (int j = 0; j < 8; ++j) {
        int c = c0 + i * 8 + j;
        float x = (bf2f((unsigned short)v[j]) - m) * rs * gamma[c] + beta[c];
        o[j] = (short)f2bf(fmaxf(x, 0.f));
      }
      lp[i] = o;
    }
  };

  auto P1 = [&](int t) {  // y1 slice = zc + [jn|pdq]@W1a + obs_t@W1o -> bf16
    int r = tid >> 3, cq = tid & 7;
    int nb = n0 + cq * 4;
    float xj[24];
#pragma unroll
    for (int j = 0; j < NJ; ++j) {
      xj[j] = (pj_l[r * NJ + j] - jm_l[j]) * jri_l[j];
      xj[12 + j] = pdq_l[r * NJ + j];
    }
    f32x4 acc = *(const f32x4*)(p.zc + (size_t)(b0 + r) * NH + nb);
    const float* w1r = p.W1 + (size_t)nb * NPIN;
#pragma unroll
    for (int k = 0; k < 24; ++k) {
      float xv = xj[k];
      acc[0] += xv * w1r[k]; acc[1] += xv * w1r[NPIN + k];
      acc[2] += xv * w1r[2 * NPIN + k]; acc[3] += xv * w1r[3 * NPIN + k];
    }
    const float* ob = p.obs + ((size_t)(b0 + r) * NS + t) * 51;
    for (int o = 0; o < 51; ++o) {
      float ov = ob[o];
      acc[0] += ov * w1r[24 + o]; acc[1] += ov * w1r[NPIN + 24 + o];
      acc[2] += ov * w1r[2 * NPIN + 24 + o]; acc[3] += ov * w1r[3 * NPIN + 24 + o];
    }
    u16x4 hv = {f2bf(acc[0]), f2bf(acc[1]), f2bf(acc[2]), f2bf(acc[3])};
    *(u16x4*)(y1bg + (size_t)r * NH + nb) = hv;
  };

  auto F2 = [&]() {  // h1 = relu(LN1(y1)) [fused]; y2 slice = h1 @ W2^T + b2
    ln_stage(y1bg, p.g1, p.be1);
    __syncthreads();
    int rt = wave >> 1, ct = wave & 1;
    int kq = (lane >> 4) * 8;
    const unsigned short* a = &albuf[(rt * 16 + (lane & 15)) * AS + kq];
    const unsigned short* b = p.w2b + (size_t)(n0 + ct * 16 + (lane & 15)) * NH + kq;
    f32x4 acc = dot1024(a, b);
    int col = n0 + ct * 16 + (lane & 15);
    float b2v = p.b2[col];
#pragma unroll
    for (int i = 0; i < 4; ++i) {
      int row = rt * 16 + (lane >> 4) * 4 + i;
      y2bg[(size_t)row * NH + col] = f2bf(acc[i] + b2v);
    }
  };

  auto F3 = [&](int t) {  // h = relu(LN2(y2)) [fused]; t1 = relu(h@Wa1^T+ba1); heads
    ln_stage(y2bg, p.g2, p.be2);
    __syncthreads();
    int rt = wave >> 1, ct = wave & 1;
    int kq = (lane >> 4) * 8;
    {
      const unsigned short* a = &albuf[(rt * 16 + (lane & 15)) * AS + kq];
      const unsigned short* b = p.wa1b + (size_t)(n0 + ct * 16 + (lane & 15)) * NH + kq;
      f32x4 acc = dot1024(a, b);
      int col = n0 + ct * 16 + (lane & 15);
      float bav = p.ba1[col];
#pragma unroll
      for (int i = 0; i < 4; ++i) {
        int row = rt * 16 + (lane >> 4) * 4 + i;
        t1g[(size_t)row * NH + col] = f2bf(fmaxf(acc[i] + bav, 0.f));
      }
    }
    if (w >= 26 && wave == 3) {  // heads: [Wo|Wv] 6 extra 16x16 tiles, A from LDS
      int e = w - 26, cte = e >> 1, rte = e & 1;
      const unsigned short* a = &albuf[(rte * 16 + (lane & 15)) * AS + kq];
      const unsigned short* b = p.wexb + (size_t)(cte * 16 + (lane & 15)) * NH + kq;
      f32x4 acc = dot1024(a, b);
      int ec = cte * 16 + (lane & 15);
#pragma unroll
      for (int i = 0; i < 4; ++i) {
        int row = rte * 16 + (lane >> 4) * 4 + i;
        int bb = b0 + row;
        if (ec < 3) {
          float val = acc[i] + bo_l[ec];
          p.out_gmu[((size_t)bb * NS + t) * NPD + 39 + ec] = (val - pm_l[39 + ec]) * psi_l[39 + ec];
        } else if (ec < 45) {
          int sv = ec - 3;
          float val = acc[i] + bv_l[sv];
          float sig = 0.05f + 0.45f / (1.f + expf(-val));
          p.out_ls[((size_t)bb * NS + t) * NPD + sv] = logf(sig);
        }
      }
    }
  };

  auto P4 = [&](int tp) {  // a = tanh(t1 @ Wa2^T + ba2); state update; outputs
    if (wave < 2) {
      int rt = wave;
      int kq = (lane >> 4) * 8;
      const unsigned short* a = t1g + (size_t)(rt * 16 + (lane & 15)) * NH + kq;
      const unsigned short* b = p.wa2b + (size_t)(lane & 15) * NH + kq;
      f32x4 acc = dot1024(a, b);
      int j = lane & 15;
      if (j < NJ) {
#pragma unroll
        for (int i = 0; i < 4; ++i) {
          int row = rt * 16 + (lane >> 4) * 4 + i;
          aex[row * 16 + j] = tanhf(acc[i] + ba2_l[j]);
        }
      }
    }
    __syncthreads();
    for (int idx = tid; idx < BROW * NJ; idx += 256) {
      int r = idx / NJ, j = idx - r * NJ;
      float av = aex[r * 16 + j];
      float pj = pj_l[idx];
      float tgt = av * 0.25f + ddp_l[j];
      float cj = pj + alpha_l[j] * (tgt - pj);
      cj = fminf(fmaxf(cj, lo_l[j]), hi_l[j]);
      pdq_l[idx] = (cj - pj) * 30.f;
      pj_l[idx] = cj;
      if (w == 0) {
        size_t o = ((size_t)(b0 + r) * NS + tp) * NJ + j;
        p.out_joint[o] = cj;
        p.out_act[o] = av;
      }
    }
    __syncthreads();
    if (w == 0) {  // agent FK + normalize -> graph_x_mu[:, :, 0:39]
      for (int idx = tid; idx < BROW * 39; idx += 256) {
        int r = idx / 39, m = idx - r * 39;
        float s = p.fkb[m];
        const float* fw = p.fkW + m * NJ;
#pragma unroll
        for (int j = 0; j < NJ; ++j) s += pj_l[r * NJ + j] * fw[j];
        p.out_gmu[((size_t)(b0 + r) * NS + tp) * NPD + m] = (s - pm_l[m]) * psi_l[m];
      }
    }
    __syncthreads();
  };

  // ---------------- step loop: 3 XCD-local barriers / step ----------------
  unsigned int nbar = 0;
  for (int t = 0; t < NS; ++t) {
    if (t > 0) P4(t - 1);           // finish prev step (t1 complete via bar C)
    P1(t);
    xbar2(sg, w, ++nbar, wave, lane);   // A: y1 complete
    F2();
    xbar2(sg, w, ++nbar, wave, lane);   // B: y2 complete
    F3(t);
    xbar2(sg, w, ++nbar, wave, lane);   // C: t1 + heads complete
  }
  P4(NS - 1);
}

extern "C" void kernel_launch(void* const* d_in, const int* in_sizes, int n_in,
                              void* d_out, int out_size, void* d_ws, size_t ws_size,
                              hipStream_t stream) {
  (void)in_sizes; (void)n_in; (void)out_size; (void)ws_size;
  char* ws = (char*)d_ws;
  Params p;
  p.z = (const float*)d_in[0];   p.obs = (const float*)d_in[1];
  p.W1 = (const float*)d_in[2];  p.b1 = (const float*)d_in[3];
  p.g1 = (const float*)d_in[4];  p.be1 = (const float*)d_in[5];
  p.W2 = (const float*)d_in[6];  p.b2 = (const float*)d_in[7];
  p.g2 = (const float*)d_in[8];  p.be2 = (const float*)d_in[9];
  p.Wa1 = (const float*)d_in[10]; p.ba1 = (const float*)d_in[11];
  p.Wa2 = (const float*)d_in[12]; p.ba2 = (const float*)d_in[13];
  p.Wo = (const float*)d_in[14]; p.bo = (const float*)d_in[15];
  p.Wv = (const float*)d_in[16]; p.bv = (const float*)d_in[17];
  p.alog = (const float*)d_in[18];
  p.fkW = (const float*)d_in[19]; p.fkb = (const float*)d_in[20];
  p.pmean = (const float*)d_in[21]; p.pstd = (const float*)d_in[22];
  p.jlo = (const float*)d_in[23]; p.jhi = (const float*)d_in[24];
  p.ddp = (const float*)d_in[25];

  float* out = (float*)d_out;
  p.out_gmu = out;                                 // [256,128,42]
  p.out_joint = out + (size_t)256 * 128 * 42;      // [256,128,12]
  p.out_act = p.out_joint + (size_t)256 * 128 * 12;
  p.out_ls = p.out_act + (size_t)256 * 128 * 12;   // [256,128,42]

  p.gcnt = (unsigned int*)(ws + 0);
  p.slots = (unsigned int*)(ws + 256);             // 8 groups x 32 slots x 64B = 16KB
  p.zc = (float*)(ws + (1 << 15));
  p.y1b = (unsigned short*)(ws + (1 << 15) + (1 << 20));
  p.y2b = (unsigned short*)(ws + (1 << 15) + (1 << 20) + (1 << 19));
  p.t1 = (unsigned short*)(ws + (1 << 15) + (1 << 20) + 2 * (1 << 19));
  p.w2b = (unsigned short*)(ws + (1 << 15) + (1 << 20) + 3 * (1 << 19));
  p.wa1b = (unsigned short*)(ws + (1 << 15) + (1 << 20) + 3 * (1 << 19) + (1 << 21));
  p.wa2b = (unsigned short*)(ws + (1 << 15) + (1 << 20) + 3 * (1 << 19) + 2 * (1 << 21));
  p.wexb = (unsigned short*)(ws + (1 << 15) + (1 << 20) + 3 * (1 << 19) + 2 * (1 << 21) + 32768);

  // counters/slots must start at 0 each call (monotonic within a call)
  hipMemsetAsync(d_ws, 0, 1 << 15, stream);
  decoder_persistent<<<dim3(256), dim3(256), 0, stream>>>(p);
}

// Round 7
// 4748.581 us; speedup vs baseline: 1.3724x; 1.3724x over previous
//
#include <hip/hip_runtime.h>
#include <math.h>

// Decoder_82231443849250: persistent-kernel recurrent MLP decoder. Round 7.
// = Round-5 structure (validated: W2 in LDS, per-row LN phases, f32 y,
//   5 XCD-local barriers/step, g=bid&7 XCD grouping) with ONE change:
// Barrier v3 (from r6, validated correct): per-WG 64B-spaced slot counters.
//   arrival = one uncontended relaxed agent-scope fetch_add on own slot
//   poll    = wave 0, per-lane global_load sc0 sc1 of all 32 slots + __all
//   acquire = buffer_inv sc0 (vector-L1-only invalidate; XCD L2 stays hot)
// All spins carry an s_memrealtime bailout so bugs terminate instead of hang.

#define NB 256
#define NS 128
#define NH 1024
#define NJ 12
#define NPIN 139
#define NPD 42
#define WPG 32
#define BROW 32
#define W2S 1032  // LDS row stride in ushorts (516 dwords = 4 mod 32 -> 2-way, free)

typedef __attribute__((ext_vector_type(8))) short short8;
typedef __attribute__((ext_vector_type(4))) float f32x4;
typedef __attribute__((ext_vector_type(4))) unsigned short u16x4;

struct Params {
  const float* z; const float* obs; const float* W1; const float* b1;
  const float* g1; const float* be1; const float* W2; const float* b2;
  const float* g2; const float* be2; const float* Wa1; const float* ba1;
  const float* Wa2; const float* ba2; const float* Wo; const float* bo;
  const float* Wv; const float* bv; const float* alog; const float* fkW;
  const float* fkb; const float* pmean; const float* pstd; const float* jlo;
  const float* jhi; const float* ddp;
  float* out_gmu; float* out_joint; float* out_act; float* out_ls;
  float* zc; float* y1; float* y2;
  unsigned short* h1; unsigned short* hh; unsigned short* t1;
  unsigned short* wa1b; unsigned short* wa2b; unsigned short* wexb;
  unsigned int* gcnt; unsigned int* slots;
};

__device__ __forceinline__ unsigned short f2bf(float x) {
  union { float f; unsigned u; } v; v.f = x;
  unsigned r = v.u + 0x7FFFu + ((v.u >> 16) & 1u);
  return (unsigned short)(r >> 16);
}

__device__ __forceinline__ f32x4 dot1024(const unsigned short* a, const unsigned short* b) {
  const short8* ap = (const short8*)a;
  const short8* bp = (const short8*)b;
  f32x4 acc0 = {0.f, 0.f, 0.f, 0.f};
  f32x4 acc1 = {0.f, 0.f, 0.f, 0.f};
#pragma unroll 4
  for (int k8 = 0; k8 < 128; k8 += 8) {
    acc0 = __builtin_amdgcn_mfma_f32_16x16x32_bf16(ap[k8], bp[k8], acc0, 0, 0, 0);
    acc1 = __builtin_amdgcn_mfma_f32_16x16x32_bf16(ap[k8 + 4], bp[k8 + 4], acc1, 0, 0, 0);
  }
  return acc0 + acc1;
}

// ---- one-time global barrier (cross-XCD safe): full fences, used once.
__device__ __forceinline__ void gbar(unsigned int* c, unsigned int target) {
  __threadfence();
  __syncthreads();
  if (threadIdx.x == 0) {
    __hip_atomic_fetch_add(c, 1u, __ATOMIC_RELEASE, __HIP_MEMORY_SCOPE_AGENT);
    unsigned long long t0 = __builtin_amdgcn_s_memrealtime();
    while (__hip_atomic_load(c, __ATOMIC_ACQUIRE, __HIP_MEMORY_SCOPE_AGENT) < target) {
      __builtin_amdgcn_s_sleep(16);
      if (__builtin_amdgcn_s_memrealtime() - t0 > (1ull << 25)) break;  // bail, never hang
    }
  }
  __syncthreads();
  __threadfence();
}

// ---- XCD-local slot barrier. sg = this group's 32-slot base (64B spacing).
__device__ __forceinline__ void xbar2(unsigned int* sg, int w, unsigned target,
                                      int wave, int lane) {
  asm volatile("s_waitcnt vmcnt(0)" ::: "memory");
  __syncthreads();
  if (wave == 0) {
    if (lane == 0)
      __hip_atomic_fetch_add(sg + (size_t)w * 16, 1u, __ATOMIC_RELAXED,
                             __HIP_MEMORY_SCOPE_AGENT);
    const unsigned int* myslot = sg + (size_t)(lane & 31) * 16;
    unsigned long long t0 = __builtin_amdgcn_s_memrealtime();
    for (;;) {
      unsigned v;
      asm volatile("global_load_dword %0, %1, off sc0 sc1\n\t"
                   "s_waitcnt vmcnt(0)"
                   : "=v"(v) : "v"(myslot) : "memory");
      if (__all(v >= target)) break;
      __builtin_amdgcn_s_sleep(1);
      if (__builtin_amdgcn_s_memrealtime() - t0 > (1ull << 23)) break;  // bail, never hang
    }
  }
  __syncthreads();
  asm volatile("buffer_inv sc0" ::: "memory");  // invalidate vector L1 only
}

__global__ __launch_bounds__(256, 2) void decoder_persistent(Params p) {
  __shared__ unsigned short w2l[BROW * W2S];          // 66048 B: W2 col-slice, bf16
  __shared__ float pj_l[BROW * NJ];
  __shared__ float pdq_l[BROW * NJ];
  __shared__ float aex[BROW * 16];
  __shared__ float redm[4], redq[4];
  __shared__ float alpha_l[NJ], jm_l[NJ], jri_l[NJ], lo_l[NJ], hi_l[NJ], ddp_l[NJ], ba2_l[NJ];
  __shared__ float pm_l[NPD], psi_l[NPD], bv_l[NPD], bo_l[4];

  const int tid = threadIdx.x;
  const int bid = blockIdx.x;
  const int g = bid & 7;        // group == XCD under default %8 round-robin
  const int w = bid >> 3;       // WG-in-group: owns cols [w*32, w*32+32)
  const int b0 = g * BROW;
  const int n0 = w * 32;
  const int wave = tid >> 6;
  const int lane = tid & 63;

  unsigned int* sg = p.slots + (size_t)g * 512;  // 32 slots x 16 dwords (64B)

  float* y1g = p.y1 + (size_t)g * BROW * NH;
  float* y2g = p.y2 + (size_t)g * BROW * NH;
  unsigned short* h1g = p.h1 + (size_t)g * BROW * NH;
  unsigned short* hg = p.hh + (size_t)g * BROW * NH;
  unsigned short* t1g = p.t1 + (size_t)g * BROW * NH;

  // ---------------- P0: one-time setup ----------------
  if (tid < NJ) {
    alpha_l[tid] = 1.f / (1.f + expf(-p.alog[tid]));
    float lo = p.jlo[tid], hi = p.jhi[tid];
    jm_l[tid] = 0.5f * (hi + lo);
    jri_l[tid] = 2.f / (hi - lo);
    lo_l[tid] = lo; hi_l[tid] = hi;
    ddp_l[tid] = p.ddp[tid]; ba2_l[tid] = p.ba2[tid];
  }
  if (tid < NPD) { pm_l[tid] = p.pmean[tid]; psi_l[tid] = 1.f / p.pstd[tid]; bv_l[tid] = p.bv[tid]; }
  if (tid < 3) bo_l[tid] = p.bo[tid];
  for (int idx = tid; idx < BROW * NJ; idx += 256) { pj_l[idx] = p.ddp[idx % NJ]; pdq_l[idx] = 0.f; }
  for (int idx = tid; idx < BROW * NH; idx += 256) {
    int r = idx >> 10, k = idx & (NH - 1);
    w2l[r * W2S + k] = f2bf(p.W2[(size_t)(n0 + r) * NH + k]);
  }
  {  // zc = z @ W1z^T + b1 (constant across steps)
    int r = tid >> 3, cq = tid & 7;
    int nb = n0 + cq * 4;
    const float* zr = p.z + (size_t)(b0 + r) * 64;
    const float* w1r = p.W1 + (size_t)nb * NPIN + 75;
    float a0 = p.b1[nb], a1 = p.b1[nb + 1], a2 = p.b1[nb + 2], a3 = p.b1[nb + 3];
    for (int k = 0; k < 64; ++k) {
      float zv = zr[k];
      a0 += zv * w1r[k]; a1 += zv * w1r[NPIN + k];
      a2 += zv * w1r[2 * NPIN + k]; a3 += zv * w1r[3 * NPIN + k];
    }
    f32x4 st = {a0, a1, a2, a3};
    *(f32x4*)(p.zc + (size_t)(b0 + r) * NH + nb) = st;
  }
  // Wa1 -> bf16 ws: rows n0+g*4..+3 over all (g,w) cover 1024 rows once
  for (int idx = tid; idx < 4 * NH; idx += 256) {
    int r = idx >> 10, k = idx & (NH - 1);
    int row = n0 + g * 4 + r;
    p.wa1b[(size_t)row * NH + k] = f2bf(p.Wa1[(size_t)row * NH + k]);
  }
  if (bid == 0) {  // Wa2 padded to 16 rows
    for (int idx = tid; idx < 16 * NH; idx += 256) {
      int r = idx >> 10, k = idx & (NH - 1);
      p.wa2b[idx] = (r < NJ) ? f2bf(p.Wa2[(size_t)r * NH + k]) : (unsigned short)0;
    }
  }
  if (bid == 1) {  // [Wo(3); Wv(42); zeros(3)] padded to 48 rows
    for (int idx = tid; idx < 48 * NH; idx += 256) {
      int r = idx >> 10, k = idx & (NH - 1);
      unsigned short v = 0;
      if (r < 3) v = f2bf(p.Wo[(size_t)r * NH + k]);
      else if (r < 45) v = f2bf(p.Wv[(size_t)(r - 3) * NH + k]);
      p.wexb[idx] = v;
    }
  }
  gbar(p.gcnt, 256u);  // one-time cross-XCD barrier (weight conversions)

  // ---------------- phase lambdas ----------------
  auto ln_row = [&](const float* y, const float* gamma, const float* beta,
                    unsigned short* hout) {
    f32x4 v = *(const f32x4*)(y + tid * 4);
    float s = v[0] + v[1] + v[2] + v[3];
    float q = v[0] * v[0] + v[1] * v[1] + v[2] * v[2] + v[3] * v[3];
#pragma unroll
    for (int off = 32; off; off >>= 1) {
      s += __shfl_down(s, off, 64);
      q += __shfl_down(q, off, 64);
    }
    if (lane == 0) { redm[wave] = s; redq[wave] = q; }
    __syncthreads();
    float m = (redm[0] + redm[1] + redm[2] + redm[3]) * (1.0f / 1024.0f);
    float e2 = (redq[0] + redq[1] + redq[2] + redq[3]) * (1.0f / 1024.0f);
    float rs = rsqrtf(e2 - m * m + 1e-5f);
    u16x4 hv;
#pragma unroll
    for (int i = 0; i < 4; ++i) {
      int c = tid * 4 + i;
      float x = (v[i] - m) * rs * gamma[c] + beta[c];
      hv[i] = f2bf(fmaxf(x, 0.f));
    }
    *(u16x4*)(hout + tid * 4) = hv;
  };

  auto P1 = [&](int t) {
    int r = tid >> 3, cq = tid & 7;
    int nb = n0 + cq * 4;
    float xj[24];
#pragma unroll
    for (int j = 0; j < NJ; ++j) {
      xj[j] = (pj_l[r * NJ + j] - jm_l[j]) * jri_l[j];
      xj[12 + j] = pdq_l[r * NJ + j];
    }
    f32x4 acc = *(const f32x4*)(p.zc + (size_t)(b0 + r) * NH + nb);
    const float* w1r = p.W1 + (size_t)nb * NPIN;
#pragma unroll
    for (int k = 0; k < 24; ++k) {
      float xv = xj[k];
      acc[0] += xv * w1r[k]; acc[1] += xv * w1r[NPIN + k];
      acc[2] += xv * w1r[2 * NPIN + k]; acc[3] += xv * w1r[3 * NPIN + k];
    }
    const float* ob = p.obs + ((size_t)(b0 + r) * NS + t) * 51;
    for (int o = 0; o < 51; ++o) {
      float ov = ob[o];
      acc[0] += ov * w1r[24 + o]; acc[1] += ov * w1r[NPIN + 24 + o];
      acc[2] += ov * w1r[2 * NPIN + 24 + o]; acc[3] += ov * w1r[3 * NPIN + 24 + o];
    }
    *(f32x4*)(y1g + (size_t)r * NH + nb) = acc;
  };

  auto P2 = [&]() {
    int rt = wave >> 1, ct = wave & 1;
    int kq = (lane >> 4) * 8;
    const unsigned short* a = h1g + (size_t)(rt * 16 + (lane & 15)) * NH + kq;
    const unsigned short* b = &w2l[(ct * 16 + (lane & 15)) * W2S + kq];
    f32x4 acc = dot1024(a, b);
    int col = n0 + ct * 16 + (lane & 15);
    float b2v = p.b2[col];
#pragma unroll
    for (int i = 0; i < 4; ++i) {
      int row = rt * 16 + (lane >> 4) * 4 + i;
      y2g[(size_t)row * NH + col] = acc[i] + b2v;
    }
  };

  auto P3 = [&](int t) {
    int rt = wave >> 1, ct = wave & 1;
    int kq = (lane >> 4) * 8;
    {
      const unsigned short* a = hg + (size_t)(rt * 16 + (lane & 15)) * NH + kq;
      const unsigned short* b = p.wa1b + (size_t)(n0 + ct * 16 + (lane & 15)) * NH + kq;
      f32x4 acc = dot1024(a, b);
      int col = n0 + ct * 16 + (lane & 15);
      float bav = p.ba1[col];
#pragma unroll
      for (int i = 0; i < 4; ++i) {
        int row = rt * 16 + (lane >> 4) * 4 + i;
        t1g[(size_t)row * NH + col] = f2bf(fmaxf(acc[i] + bav, 0.f));
      }
    }
    if (w >= 26 && wave == 3) {  // heads: [Wo|Wv] 6 extra 16x16 tiles
      int e = w - 26, cte = e >> 1, rte = e & 1;
      const unsigned short* a = hg + (size_t)(rte * 16 + (lane & 15)) * NH + kq;
      const unsigned short* b = p.wexb + (size_t)(cte * 16 + (lane & 15)) * NH + kq;
      f32x4 acc = dot1024(a, b);
      int ec = cte * 16 + (lane & 15);
#pragma unroll
      for (int i = 0; i < 4; ++i) {
        int row = rte * 16 + (lane >> 4) * 4 + i;
        int bb = b0 + row;
        if (ec < 3) {
          float val = acc[i] + bo_l[ec];
          p.out_gmu[((size_t)bb * NS + t) * NPD + 39 + ec] = (val - pm_l[39 + ec]) * psi_l[39 + ec];
        } else if (ec < 45) {
          int sv = ec - 3;
          float val = acc[i] + bv_l[sv];
          float sig = 0.05f + 0.45f / (1.f + expf(-val));
          p.out_ls[((size_t)bb * NS + t) * NPD + sv] = logf(sig);
        }
      }
    }
  };

  auto P4 = [&](int tp) {
    if (wave < 2) {
      int rt = wave;
      int kq = (lane >> 4) * 8;
      const unsigned short* a = t1g + (size_t)(rt * 16 + (lane & 15)) * NH + kq;
      const unsigned short* b = p.wa2b + (size_t)(lane & 15) * NH + kq;
      f32x4 acc = dot1024(a, b);
      int j = lane & 15;
      if (j < NJ) {
#pragma unroll
        for (int i = 0; i < 4; ++i) {
          int row = rt * 16 + (lane >> 4) * 4 + i;
          aex[row * 16 + j] = tanhf(acc[i] + ba2_l[j]);
        }
      }
    }
    __syncthreads();
    for (int idx = tid; idx < BROW * NJ; idx += 256) {
      int r = idx / NJ, j = idx - r * NJ;
      float av = aex[r * 16 + j];
      float pj = pj_l[idx];
      float tgt = av * 0.25f + ddp_l[j];
      float cj = pj + alpha_l[j] * (tgt - pj);
      cj = fminf(fmaxf(cj, lo_l[j]), hi_l[j]);
      pdq_l[idx] = (cj - pj) * 30.f;
      pj_l[idx] = cj;
      if (w == 0) {
        size_t o = ((size_t)(b0 + r) * NS + tp) * NJ + j;
        p.out_joint[o] = cj;
        p.out_act[o] = av;
      }
    }
    __syncthreads();
    if (w == 0) {
      for (int idx = tid; idx < BROW * 39; idx += 256) {
        int r = idx / 39, m = idx - r * 39;
        float s = p.fkb[m];
        const float* fw = p.fkW + m * NJ;
#pragma unroll
        for (int j = 0; j < NJ; ++j) s += pj_l[r * NJ + j] * fw[j];
        p.out_gmu[((size_t)(b0 + r) * NS + tp) * NPD + m] = (s - pm_l[m]) * psi_l[m];
      }
    }
    __syncthreads();
  };

  // ---------------- step loop: 5 XCD-local slot barriers / step ----------------
  unsigned int nbar = 0;
  for (int t = 0; t < NS; ++t) {
    if (t > 0) P4(t - 1);
    P1(t);
    xbar2(sg, w, ++nbar, wave, lane);   // y1 complete
    ln_row(y1g + (size_t)w * NH, p.g1, p.be1, h1g + (size_t)w * NH);
    xbar2(sg, w, ++nbar, wave, lane);   // h1 complete
    P2();
    xbar2(sg, w, ++nbar, wave, lane);   // y2 complete
    ln_row(y2g + (size_t)w * NH, p.g2, p.be2, hg + (size_t)w * NH);
    xbar2(sg, w, ++nbar, wave, lane);   // h complete
    P3(t);
    xbar2(sg, w, ++nbar, wave, lane);   // t1 + heads complete
  }
  P4(NS - 1);
}

extern "C" void kernel_launch(void* const* d_in, const int* in_sizes, int n_in,
                              void* d_out, int out_size, void* d_ws, size_t ws_size,
                              hipStream_t stream) {
  (void)in_sizes; (void)n_in; (void)out_size; (void)ws_size;
  char* ws = (char*)d_ws;
  Params p;
  p.z = (const float*)d_in[0];   p.obs = (const float*)d_in[1];
  p.W1 = (const float*)d_in[2];  p.b1 = (const float*)d_in[3];
  p.g1 = (const float*)d_in[4];  p.be1 = (const float*)d_in[5];
  p.W2 = (const float*)d_in[6];  p.b2 = (const float*)d_in[7];
  p.g2 = (const float*)d_in[8];  p.be2 = (const float*)d_in[9];
  p.Wa1 = (const float*)d_in[10]; p.ba1 = (const float*)d_in[11];
  p.Wa2 = (const float*)d_in[12]; p.ba2 = (const float*)d_in[13];
  p.Wo = (const float*)d_in[14]; p.bo = (const float*)d_in[15];
  p.Wv = (const float*)d_in[16]; p.bv = (const float*)d_in[17];
  p.alog = (const float*)d_in[18];
  p.fkW = (const float*)d_in[19]; p.fkb = (const float*)d_in[20];
  p.pmean = (const float*)d_in[21]; p.pstd = (const float*)d_in[22];
  p.jlo = (const float*)d_in[23]; p.jhi = (const float*)d_in[24];
  p.ddp = (const float*)d_in[25];

  float* out = (float*)d_out;
  p.out_gmu = out;                                 // [256,128,42]
  p.out_joint = out + (size_t)256 * 128 * 42;      // [256,128,12]
  p.out_act = p.out_joint + (size_t)256 * 128 * 12;
  p.out_ls = p.out_act + (size_t)256 * 128 * 12;   // [256,128,42]

  p.gcnt = (unsigned int*)(ws + 0);
  p.slots = (unsigned int*)(ws + 1024);            // 8 groups x 32 slots x 64B = 16KB
  p.zc = (float*)(ws + (1 << 15));
  p.y1 = (float*)(ws + (1 << 15) + (1 << 20));
  p.y2 = (float*)(ws + (1 << 15) + 2 * (1 << 20));
  p.h1 = (unsigned short*)(ws + (1 << 15) + 3 * (1 << 20));
  p.hh = (unsigned short*)(ws + (1 << 15) + 3 * (1 << 20) + (1 << 19));
  p.t1 = (unsigned short*)(ws + (1 << 15) + 3 * (1 << 20) + 2 * (1 << 19));
  p.wa1b = (unsigned short*)(ws + (1 << 15) + 3 * (1 << 20) + 3 * (1 << 19));
  p.wa2b = (unsigned short*)(ws + (1 << 15) + 5 * (1 << 20) + 3 * (1 << 19));
  p.wexb = (unsigned short*)(ws + (1 << 15) + 5 * (1 << 20) + 3 * (1 << 19) + 32768);

  // counters/slots must start at 0 each call (monotonic within a call)
  hipMemsetAsync(d_ws, 0, 1 << 15, stream);
  decoder_persistent<<<dim3(256), dim3(256), 0, stream>>>(p);
}

// Round 8
// 3873.275 us; speedup vs baseline: 1.6826x; 1.2260x over previous
//
#include <hip/hip_runtime.h>
#include <math.h>

// Decoder_82231443849250: persistent-kernel recurrent MLP decoder. Round 8.
// 8 batch-groups (32 rows) x 32 WGs (32-col slices); g = bid&7 (XCD-aligned,
// validated r4-r7). 3 XCD-local slot barriers per step (was 5):
//   X: reduce pa partials (sc0) -> tanh -> state -> outputs(t-1); P1 -> y1 bf16
//   barA
//   Y: stage y1 (sc0) + fused LN1 -> albuf(LDS); GEMM vs W2(LDS) -> y2 bf16
//   barB
//   Z: stage y2 + fused LN2 -> albuf; GEMM vs Wa1(global,L1-hot) -> t1(LDS);
//      one MFMA vs Wa2 slice(LDS) -> pa partials; heads (WGs 26-31) from albuf
//   barC
// NO buffer_inv anywhere: cross-WG-fresh data (y1,y2,pa) is read with explicit
// sc0 loads (L1-bypass, XCD-L2 hit); weights stay L1-resident across steps.
// All spins carry an s_memrealtime bailout so bugs terminate instead of hang.

#define NB 256
#define NS 128
#define NH 1024
#define NJ 12
#define NPIN 139
#define NPD 42
#define WPG 32
#define BROW 32
#define W2S 1032
#define AS 1032

typedef __attribute__((ext_vector_type(8))) short short8;
typedef __attribute__((ext_vector_type(4))) float f32x4;
typedef __attribute__((ext_vector_type(4))) unsigned short u16x4;

struct Params {
  const float* z; const float* obs; const float* W1; const float* b1;
  const float* g1; const float* be1; const float* W2; const float* b2;
  const float* g2; const float* be2; const float* Wa1; const float* ba1;
  const float* Wa2; const float* ba2; const float* Wo; const float* bo;
  const float* Wv; const float* bv; const float* alog; const float* fkW;
  const float* fkb; const float* pmean; const float* pstd; const float* jlo;
  const float* jhi; const float* ddp;
  float* out_gmu; float* out_joint; float* out_act; float* out_ls;
  float* zc; float* pa;
  unsigned short* y1b; unsigned short* y2b;
  unsigned short* wa1b; unsigned short* wexb;
  unsigned int* gcnt; unsigned int* slots;
};

__device__ __forceinline__ unsigned short f2bf(float x) {
  union { float f; unsigned u; } v; v.f = x;
  unsigned r = v.u + 0x7FFFu + ((v.u >> 16) & 1u);
  return (unsigned short)(r >> 16);
}
__device__ __forceinline__ float bf2f(unsigned short x) {
  union { unsigned u; float f; } v; v.u = ((unsigned)x) << 16;
  return v.f;
}
__device__ __forceinline__ unsigned cvt_pk_bf16(float lo, float hi) {
  unsigned r;
  asm("v_cvt_pk_bf16_f32 %0, %1, %2" : "=v"(r) : "v"(lo), "v"(hi));
  return r;
}
// sc0 loads: bypass vector L1, read the (shared, intra-XCD-coherent) L2.
__device__ __forceinline__ void ld16_sc0(const unsigned short* p, short8& d) {
  asm volatile("global_load_dwordx4 %0, %1, off sc0" : "=v"(d) : "v"(p));
}
__device__ __forceinline__ void ldf4_sc0(const float* p, f32x4& d) {
  asm volatile("global_load_dwordx4 %0, %1, off sc0" : "=v"(d) : "v"(p));
}
__device__ __forceinline__ void vwait0() {
  asm volatile("s_waitcnt vmcnt(0)" ::: "memory");
  __builtin_amdgcn_sched_barrier(0);  // rule #18: pin uses after the wait
}

__device__ __forceinline__ f32x4 dot1024(const unsigned short* a, const unsigned short* b) {
  const short8* ap = (const short8*)a;
  const short8* bp = (const short8*)b;
  f32x4 acc0 = {0.f, 0.f, 0.f, 0.f};
  f32x4 acc1 = {0.f, 0.f, 0.f, 0.f};
#pragma unroll 4
  for (int k8 = 0; k8 < 128; k8 += 8) {
    acc0 = __builtin_amdgcn_mfma_f32_16x16x32_bf16(ap[k8], bp[k8], acc0, 0, 0, 0);
    acc1 = __builtin_amdgcn_mfma_f32_16x16x32_bf16(ap[k8 + 4], bp[k8 + 4], acc1, 0, 0, 0);
  }
  return acc0 + acc1;
}

// ---- one-time global barrier (cross-XCD safe): full fences, used once.
__device__ __forceinline__ void gbar(unsigned int* c, unsigned int target) {
  __threadfence();
  __syncthreads();
  if (threadIdx.x == 0) {
    __hip_atomic_fetch_add(c, 1u, __ATOMIC_RELEASE, __HIP_MEMORY_SCOPE_AGENT);
    unsigned long long t0 = __builtin_amdgcn_s_memrealtime();
    while (__hip_atomic_load(c, __ATOMIC_ACQUIRE, __HIP_MEMORY_SCOPE_AGENT) < target) {
      __builtin_amdgcn_s_sleep(16);
      if (__builtin_amdgcn_s_memrealtime() - t0 > (1ull << 25)) break;
    }
  }
  __syncthreads();
  __threadfence();
}

// ---- XCD-local slot barrier (r7-validated), minus buffer_inv.
__device__ __forceinline__ void xbar2(unsigned int* sg, int w, unsigned target,
                                      int wave, int lane) {
  asm volatile("s_waitcnt vmcnt(0)" ::: "memory");
  __syncthreads();
  if (wave == 0) {
    if (lane == 0)
      __hip_atomic_fetch_add(sg + (size_t)w * 16, 1u, __ATOMIC_RELAXED,
                             __HIP_MEMORY_SCOPE_AGENT);
    const unsigned int* myslot = sg + (size_t)(lane & 31) * 16;
    unsigned long long t0 = __builtin_amdgcn_s_memrealtime();
    for (;;) {
      unsigned v;
      asm volatile("global_load_dword %0, %1, off sc0 sc1\n\t"
                   "s_waitcnt vmcnt(0)"
                   : "=v"(v) : "v"(myslot) : "memory");
      if (__all(v >= target)) break;
      __builtin_amdgcn_s_sleep(1);
      if (__builtin_amdgcn_s_memrealtime() - t0 > (1ull << 23)) break;
    }
  }
  __syncthreads();
}

__global__ __launch_bounds__(256, 1) void decoder_persistent(Params p) {
  __shared__ unsigned short w2l[BROW * W2S];    // 66 KB: W2 col-slice bf16
  __shared__ unsigned short albuf[BROW * AS];   // 66 KB: normalized A tile bf16
  __shared__ float g1l[NH], be1l[NH], g2l[NH], be2l[NH];  // 16 KB
  __shared__ unsigned short t1l[BROW * 40];     // 2.5 KB
  __shared__ unsigned short wa2l[16 * 40];      // 1.25 KB
  __shared__ float pj_l[BROW * NJ], pdq_l[BROW * NJ];
  __shared__ float alpha_l[NJ], jm_l[NJ], jri_l[NJ], lo_l[NJ], hi_l[NJ], ddp_l[NJ], ba2_l[NJ];
  __shared__ float pm_l[NPD], psi_l[NPD], bv_l[NPD], bo_l[4];

  const int tid = threadIdx.x;
  const int bid = blockIdx.x;
  const int g = bid & 7;
  const int w = bid >> 3;
  const int b0 = g * BROW;
  const int n0 = w * 32;
  const int wave = tid >> 6;
  const int lane = tid & 63;

  unsigned int* sg = p.slots + (size_t)g * 512;
  unsigned short* y1bg = p.y1b + (size_t)g * BROW * NH;
  unsigned short* y2bg = p.y2b + (size_t)g * BROW * NH;
  float* pa_gg = p.pa + (size_t)g * BROW * NJ * 32;

  // ---------------- P0: one-time setup ----------------
  if (tid < NJ) {
    alpha_l[tid] = 1.f / (1.f + expf(-p.alog[tid]));
    float lo = p.jlo[tid], hi = p.jhi[tid];
    jm_l[tid] = 0.5f * (hi + lo);
    jri_l[tid] = 2.f / (hi - lo);
    lo_l[tid] = lo; hi_l[tid] = hi;
    ddp_l[tid] = p.ddp[tid]; ba2_l[tid] = p.ba2[tid];
  }
  if (tid < NPD) { pm_l[tid] = p.pmean[tid]; psi_l[tid] = 1.f / p.pstd[tid]; bv_l[tid] = p.bv[tid]; }
  if (tid < 3) bo_l[tid] = p.bo[tid];
  for (int idx = tid; idx < BROW * NJ; idx += 256) { pj_l[idx] = p.ddp[idx % NJ]; pdq_l[idx] = 0.f; }
  for (int idx = tid; idx < NH; idx += 256) {
    g1l[idx] = p.g1[idx]; be1l[idx] = p.be1[idx];
    g2l[idx] = p.g2[idx]; be2l[idx] = p.be2[idx];
  }
  for (int idx = tid; idx < BROW * NH; idx += 256) {
    int r = idx >> 10, k = idx & (NH - 1);
    w2l[r * W2S + k] = f2bf(p.W2[(size_t)(n0 + r) * NH + k]);
  }
  for (int idx = tid; idx < 16 * 32; idx += 256) {   // Wa2 slice -> LDS (padded rows 12..15 = 0)
    int rr = idx >> 5, cc = idx & 31;
    wa2l[rr * 40 + cc] = (rr < NJ) ? f2bf(p.Wa2[(size_t)rr * NH + n0 + cc]) : (unsigned short)0;
  }
  {  // zc = z @ W1z^T + b1 (constant across steps)
    int r = tid >> 3, cq = tid & 7;
    int nb = n0 + cq * 4;
    const float* zr = p.z + (size_t)(b0 + r) * 64;
    const float* w1r = p.W1 + (size_t)nb * NPIN + 75;
    float a0 = p.b1[nb], a1 = p.b1[nb + 1], a2 = p.b1[nb + 2], a3 = p.b1[nb + 3];
    for (int k = 0; k < 64; ++k) {
      float zv = zr[k];
      a0 += zv * w1r[k]; a1 += zv * w1r[NPIN + k];
      a2 += zv * w1r[2 * NPIN + k]; a3 += zv * w1r[3 * NPIN + k];
    }
    f32x4 st = {a0, a1, a2, a3};
    *(f32x4*)(p.zc + (size_t)(b0 + r) * NH + nb) = st;
  }
  for (int idx = tid; idx < 4 * NH; idx += 256) {  // Wa1 -> bf16 ws (cooperative)
    int r = idx >> 10, k = idx & (NH - 1);
    int row = n0 + g * 4 + r;
    p.wa1b[(size_t)row * NH + k] = f2bf(p.Wa1[(size_t)row * NH + k]);
  }
  if (bid == 1) {  // [Wo(3); Wv(42); zeros(3)] padded to 48 rows
    for (int idx = tid; idx < 48 * NH; idx += 256) {
      int r = idx >> 10, k = idx & (NH - 1);
      unsigned short v = 0;
      if (r < 3) v = f2bf(p.Wo[(size_t)r * NH + k]);
      else if (r < 45) v = f2bf(p.Wv[(size_t)(r - 3) * NH + k]);
      p.wexb[idx] = v;
    }
  }
  gbar(p.gcnt, 256u);

  // ---------------- phase lambdas ----------------
  // Stage full y tile (bf16, via sc0) into albuf with fused LayerNorm+ReLU.
  // Thread (r=tid>>3, cq=tid&7): row r, cols cq*8 + i*64 (i=0..15).
  auto stage_ln = [&](const unsigned short* yg, const float* gl, const float* bl) {
    const int r = tid >> 3, cq = tid & 7;
    const unsigned short* src = yg + (size_t)r * NH + cq * 8;
    unsigned short* dst = &albuf[r * AS + cq * 8];
    short8 v[16];
#pragma unroll
    for (int i = 0; i < 16; ++i) ld16_sc0(src + (size_t)i * 64, v[i]);
    vwait0();
    float s = 0.f, q = 0.f;
#pragma unroll
    for (int i = 0; i < 16; ++i)
#pragma unroll
      for (int jj = 0; jj < 8; ++jj) {
        float x = bf2f((unsigned short)v[i][jj]);
        s += x; q = fmaf(x, x, q);
      }
#pragma unroll
    for (int off = 4; off; off >>= 1) {
      s += __shfl_down(s, off, 8);
      q += __shfl_down(q, off, 8);
    }
    s = __shfl(s, 0, 8); q = __shfl(q, 0, 8);
    float m = s * (1.f / 1024.f);
    float rs = rsqrtf(q * (1.f / 1024.f) - m * m + 1e-5f);
    float nmrs = -m * rs;
#pragma unroll
    for (int i = 0; i < 16; ++i) {
      int c = cq * 8 + i * 64;
      f32x4 ga = *(const f32x4*)(gl + c);       // broadcast across the 8 r-lanes
      f32x4 gb = *(const f32x4*)(gl + c + 4);
      f32x4 ba = *(const f32x4*)(bl + c);
      f32x4 bb = *(const f32x4*)(bl + c + 4);
      float xn[8];
#pragma unroll
      for (int jj = 0; jj < 8; ++jj) {
        float x = bf2f((unsigned short)v[i][jj]);
        float tn = fmaf(x, rs, nmrs);
        float gg = (jj < 4) ? ga[jj] : gb[jj - 4];
        float bv2 = (jj < 4) ? ba[jj] : bb[jj - 4];
        xn[jj] = fmaxf(fmaf(tn, gg, bv2), 0.f);
      }
      uint4 pk = {cvt_pk_bf16(xn[0], xn[1]), cvt_pk_bf16(xn[2], xn[3]),
                  cvt_pk_bf16(xn[4], xn[5]), cvt_pk_bf16(xn[6], xn[7])};
      *(uint4*)(dst + i * 64) = pk;
    }
  };

  auto P1 = [&](int t) {  // y1 slice = zc + [jn|pdq]@W1a + obs_t@W1o -> bf16
    int r = tid >> 3, cq = tid & 7;
    int nb = n0 + cq * 4;
    float xj[24];
#pragma unroll
    for (int j = 0; j < NJ; ++j) {
      xj[j] = (pj_l[r * NJ + j] - jm_l[j]) * jri_l[j];
      xj[12 + j] = pdq_l[r * NJ + j];
    }
    f32x4 acc = *(const f32x4*)(p.zc + (size_t)(b0 + r) * NH + nb);
    const float* w1r = p.W1 + (size_t)nb * NPIN;
#pragma unroll
    for (int k = 0; k < 24; ++k) {
      float xv = xj[k];
      acc[0] += xv * w1r[k]; acc[1] += xv * w1r[NPIN + k];
      acc[2] += xv * w1r[2 * NPIN + k]; acc[3] += xv * w1r[3 * NPIN + k];
    }
    const float* ob = p.obs + ((size_t)(b0 + r) * NS + t) * 51;
    for (int o = 0; o < 51; ++o) {
      float ov = ob[o];
      acc[0] += ov * w1r[24 + o]; acc[1] += ov * w1r[NPIN + 24 + o];
      acc[2] += ov * w1r[2 * NPIN + 24 + o]; acc[3] += ov * w1r[3 * NPIN + 24 + o];
    }
    u16x4 hv = {f2bf(acc[0]), f2bf(acc[1]), f2bf(acc[2]), f2bf(acc[3])};
    *(u16x4*)(y1bg + (size_t)r * NH + nb) = hv;
  };

  auto Yphase = [&]() {  // h1 = relu(LN1(y1)); y2 slice = h1 @ W2^T + b2
    stage_ln(y1bg, g1l, be1l);
    __syncthreads();
    int rt = wave >> 1, ct = wave & 1;
    int kq = (lane >> 4) * 8;
    const unsigned short* a = &albuf[(rt * 16 + (lane & 15)) * AS + kq];
    const unsigned short* b = &w2l[(ct * 16 + (lane & 15)) * W2S + kq];
    f32x4 acc = dot1024(a, b);
    int col = n0 + ct * 16 + (lane & 15);
    float b2v = p.b2[col];
#pragma unroll
    for (int i = 0; i < 4; ++i) {
      int row = rt * 16 + (lane >> 4) * 4 + i;
      y2bg[(size_t)row * NH + col] = f2bf(acc[i] + b2v);
    }
  };

  auto Zphase = [&](int t) {  // h = relu(LN2(y2)); t1 -> LDS; pa partials; heads
    stage_ln(y2bg, g2l, be2l);
    __syncthreads();
    int rt = wave >> 1, ct = wave & 1;
    int kq = (lane >> 4) * 8;
    {
      const unsigned short* a = &albuf[(rt * 16 + (lane & 15)) * AS + kq];
      const unsigned short* b = p.wa1b + (size_t)(n0 + ct * 16 + (lane & 15)) * NH + kq;
      f32x4 acc = dot1024(a, b);
      int lcol = ct * 16 + (lane & 15);
      float bav = p.ba1[n0 + lcol];
#pragma unroll
      for (int i = 0; i < 4; ++i) {
        int row = rt * 16 + (lane >> 4) * 4 + i;
        t1l[row * 40 + lcol] = f2bf(fmaxf(acc[i] + bav, 0.f));
      }
    }
    __syncthreads();
    if (wave < 2) {  // pa[32 rows][12 j] partial over this WG's 32 cols: 1 MFMA
      int k0 = (lane >> 4) * 8;
      short8 a8 = *(const short8*)&t1l[(wave * 16 + (lane & 15)) * 40 + k0];
      short8 b8 = *(const short8*)&wa2l[(lane & 15) * 40 + k0];
      f32x4 z4 = {0.f, 0.f, 0.f, 0.f};
      f32x4 d = __builtin_amdgcn_mfma_f32_16x16x32_bf16(a8, b8, z4, 0, 0, 0);
      int j = lane & 15;
      if (j < NJ) {
#pragma unroll
        for (int i = 0; i < 4; ++i) {
          int row = wave * 16 + (lane >> 4) * 4 + i;
          pa_gg[((size_t)row * NJ + j) * 32 + w] = d[i];
        }
      }
    }
    if (w >= 26 && wave == 3) {  // heads: [Wo|Wv] 6 extra 16x16 tiles off albuf
      int e = w - 26, cte = e >> 1, rte = e & 1;
      const unsigned short* a = &albuf[(rte * 16 + (lane & 15)) * AS + kq];
      const unsigned short* b = p.wexb + (size_t)(cte * 16 + (lane & 15)) * NH + kq;
      f32x4 acc = dot1024(a, b);
      int ec = cte * 16 + (lane & 15);
#pragma unroll
      for (int i = 0; i < 4; ++i) {
        int row = rte * 16 + (lane >> 4) * 4 + i;
        int bb = b0 + row;
        if (ec < 3) {
          float val = acc[i] + bo_l[ec];
          p.out_gmu[((size_t)bb * NS + t) * NPD + 39 + ec] = (val - pm_l[39 + ec]) * psi_l[39 + ec];
        } else if (ec < 45) {
          int sv = ec - 3;
          float val = acc[i] + bv_l[sv];
          float sig = 0.05f + 0.45f / (1.f + expf(-val));
          p.out_ls[((size_t)bb * NS + t) * NPD + sv] = logf(sig);
        }
      }
    }
  };

  auto Xmid = [&](int tp) {  // reduce pa -> a; state update; outputs for step tp
    for (int e = tid; e < BROW * NJ; e += 256) {
      const float* pp = pa_gg + (size_t)e * 32;
      f32x4 u[8];
#pragma unroll
      for (int c2 = 0; c2 < 8; ++c2) ldf4_sc0(pp + c2 * 4, u[c2]);
      vwait0();
      f32x4 ss = ((u[0] + u[1]) + (u[2] + u[3])) + ((u[4] + u[5]) + (u[6] + u[7]));
      float sum = ss[0] + ss[1] + ss[2] + ss[3];
      int r = e / NJ, j = e - r * NJ;
      float av = tanhf(sum + ba2_l[j]);
      float pj = pj_l[e];
      float tgt = av * 0.25f + ddp_l[j];
      float cj = pj + alpha_l[j] * (tgt - pj);
      cj = fminf(fmaxf(cj, lo_l[j]), hi_l[j]);
      pdq_l[e] = (cj - pj) * 30.f;
      pj_l[e] = cj;
      if (w == 0) {
        size_t o = ((size_t)(b0 + r) * NS + tp) * NJ + j;
        p.out_joint[o] = cj;
        p.out_act[o] = av;
      }
    }
    __syncthreads();
    if (w == 0) {  // agent FK + normalize -> graph_x_mu[:, :, 0:39]
      for (int idx = tid; idx < BROW * 39; idx += 256) {
        int r = idx / 39, m = idx - r * 39;
        float s = p.fkb[m];
        const float* fw = p.fkW + m * NJ;
#pragma unroll
        for (int j = 0; j < NJ; ++j) s += pj_l[r * NJ + j] * fw[j];
        p.out_gmu[((size_t)(b0 + r) * NS + tp) * NPD + m] = (s - pm_l[m]) * psi_l[m];
      }
    }
  };

  // ---------------- step loop: 3 XCD-local barriers / step ----------------
  unsigned int nbar = 0;
  for (int t = 0; t < NS; ++t) {
    if (t > 0) Xmid(t - 1);
    P1(t);
    xbar2(sg, w, ++nbar, wave, lane);   // A: y1 complete
    Yphase();
    xbar2(sg, w, ++nbar, wave, lane);   // B: y2 complete
    Zphase(t);
    xbar2(sg, w, ++nbar, wave, lane);   // C: pa + heads complete
  }
  Xmid(NS - 1);
}

extern "C" void kernel_launch(void* const* d_in, const int* in_sizes, int n_in,
                              void* d_out, int out_size, void* d_ws, size_t ws_size,
                              hipStream_t stream) {
  (void)in_sizes; (void)n_in; (void)out_size; (void)ws_size;
  char* ws = (char*)d_ws;
  Params p;
  p.z = (const float*)d_in[0];   p.obs = (const float*)d_in[1];
  p.W1 = (const float*)d_in[2];  p.b1 = (const float*)d_in[3];
  p.g1 = (const float*)d_in[4];  p.be1 = (const float*)d_in[5];
  p.W2 = (const float*)d_in[6];  p.b2 = (const float*)d_in[7];
  p.g2 = (const float*)d_in[8];  p.be2 = (const float*)d_in[9];
  p.Wa1 = (const float*)d_in[10]; p.ba1 = (const float*)d_in[11];
  p.Wa2 = (const float*)d_in[12]; p.ba2 = (const float*)d_in[13];
  p.Wo = (const float*)d_in[14]; p.bo = (const float*)d_in[15];
  p.Wv = (const float*)d_in[16]; p.bv = (const float*)d_in[17];
  p.alog = (const float*)d_in[18];
  p.fkW = (const float*)d_in[19]; p.fkb = (const float*)d_in[20];
  p.pmean = (const float*)d_in[21]; p.pstd = (const float*)d_in[22];
  p.jlo = (const float*)d_in[23]; p.jhi = (const float*)d_in[24];
  p.ddp = (const float*)d_in[25];

  float* out = (float*)d_out;
  p.out_gmu = out;                                 // [256,128,42]
  p.out_joint = out + (size_t)256 * 128 * 42;      // [256,128,12]
  p.out_act = p.out_joint + (size_t)256 * 128 * 12;
  p.out_ls = p.out_act + (size_t)256 * 128 * 12;   // [256,128,42]

  p.gcnt = (unsigned int*)(ws + 0);
  p.slots = (unsigned int*)(ws + 1024);            // 8 x 32 x 64B = 16KB
  size_t off = (size_t)1 << 15;
  p.zc = (float*)(ws + off);                 off += (size_t)NB * NH * 4;       // 1MB
  p.y1b = (unsigned short*)(ws + off);       off += (size_t)NB * NH * 2;       // 512KB
  p.y2b = (unsigned short*)(ws + off);       off += (size_t)NB * NH * 2;       // 512KB
  p.pa = (float*)(ws + off);                 off += (size_t)8 * 32 * 12 * 32 * 4; // 384KB
  p.wa1b = (unsigned short*)(ws + off);      off += (size_t)NH * NH * 2;       // 2MB
  p.wexb = (unsigned short*)(ws + off);

  // counters/slots must start at 0 each call (monotonic within a call)
  hipMemsetAsync(d_ws, 0, 1 << 15, stream);
  decoder_persistent<<<dim3(256), dim3(256), 0, stream>>>(p);
}

// Round 10
// 3672.994 us; speedup vs baseline: 1.7743x; 1.0545x over previous
//
#include <hip/hip_runtime.h>
#include <math.h>

// Decoder_82231443849250: persistent-kernel recurrent MLP decoder. Round 10.
// = Round-8 structure + r9's LN-stats partials, with the barrier REVERTED to
//   the r8-proven form (arrival = relaxed agent-scope atomic fetch_add on own
//   64B slot -> executes at device coherence point; poll = per-lane
//   global_load sc0 sc1 of all 32 slots + __all). r9 lesson: sc0-only loads
//   can be served stale from the polling CU's L1 (slot line never evicted);
//   sc1 is required on the poll. Data-path sc0 loads are fresh-by-eviction
//   (each phase streams >=128KB through the 32KB L1) - validated r4-r8.
// NEW: split-phase barrier C - arrive after pa drains, overlap the
//   state-independent obs-dot of P1(t+1) with the barrier settle, wait, then
//   Xmid + state-dependent P1 finish.
// All spins carry an s_memrealtime bailout so bugs terminate instead of hang.

#define NB 256
#define NS 128
#define NH 1024
#define NJ 12
#define NPIN 139
#define NPD 42
#define WPG 32
#define BROW 32
#define W2S 1032
#define AS 1032

typedef __attribute__((ext_vector_type(8))) short short8;
typedef __attribute__((ext_vector_type(4))) float f32x4;
typedef __attribute__((ext_vector_type(4))) unsigned short u16x4;

struct Params {
  const float* z; const float* obs; const float* W1; const float* b1;
  const float* g1; const float* be1; const float* W2; const float* b2;
  const float* g2; const float* be2; const float* Wa1; const float* ba1;
  const float* Wa2; const float* ba2; const float* Wo; const float* bo;
  const float* Wv; const float* bv; const float* alog; const float* fkW;
  const float* fkb; const float* pmean; const float* pstd; const float* jlo;
  const float* jhi; const float* ddp;
  float* out_gmu; float* out_joint; float* out_act; float* out_ls;
  float* zc; float* pa; float* part1; float* part2;
  unsigned short* y1b; unsigned short* y2b;
  unsigned short* wa1b; unsigned short* wexb;
  unsigned int* gcnt; unsigned int* slots;
};

__device__ __forceinline__ unsigned short f2bf(float x) {
  union { float f; unsigned u; } v; v.f = x;
  unsigned r = v.u + 0x7FFFu + ((v.u >> 16) & 1u);
  return (unsigned short)(r >> 16);
}
__device__ __forceinline__ float bf2f(unsigned short x) {
  union { unsigned u; float f; } v; v.u = ((unsigned)x) << 16;
  return v.f;
}
__device__ __forceinline__ unsigned cvt_pk_bf16(float lo, float hi) {
  unsigned r;
  asm("v_cvt_pk_bf16_f32 %0, %1, %2" : "=v"(r) : "v"(lo), "v"(hi));
  return r;
}
// sc0 loads: bypass stale-L1-by-eviction (see header caveat), hit XCD L2.
__device__ __forceinline__ void ld16_sc0(const unsigned short* p, short8& d) {
  asm volatile("global_load_dwordx4 %0, %1, off sc0" : "=v"(d) : "v"(p));
}
__device__ __forceinline__ void ldf4_sc0(const float* p, f32x4& d) {
  asm volatile("global_load_dwordx4 %0, %1, off sc0" : "=v"(d) : "v"(p));
}
__device__ __forceinline__ void vwait0() {
  asm volatile("s_waitcnt vmcnt(0)" ::: "memory");
  __builtin_amdgcn_sched_barrier(0);  // rule #18: pin uses after the wait
}

__device__ __forceinline__ f32x4 dot1024(const unsigned short* a, const unsigned short* b) {
  const short8* ap = (const short8*)a;
  const short8* bp = (const short8*)b;
  f32x4 acc0 = {0.f, 0.f, 0.f, 0.f};
  f32x4 acc1 = {0.f, 0.f, 0.f, 0.f};
#pragma unroll 4
  for (int k8 = 0; k8 < 128; k8 += 8) {
    acc0 = __builtin_amdgcn_mfma_f32_16x16x32_bf16(ap[k8], bp[k8], acc0, 0, 0, 0);
    acc1 = __builtin_amdgcn_mfma_f32_16x16x32_bf16(ap[k8 + 4], bp[k8 + 4], acc1, 0, 0, 0);
  }
  return acc0 + acc1;
}

// ---- one-time global barrier (cross-XCD safe): full fences, used once.
__device__ __forceinline__ void gbar(unsigned int* c, unsigned int target) {
  __threadfence();
  __syncthreads();
  if (threadIdx.x == 0) {
    __hip_atomic_fetch_add(c, 1u, __ATOMIC_RELEASE, __HIP_MEMORY_SCOPE_AGENT);
    unsigned long long t0 = __builtin_amdgcn_s_memrealtime();
    while (__hip_atomic_load(c, __ATOMIC_ACQUIRE, __HIP_MEMORY_SCOPE_AGENT) < target) {
      __builtin_amdgcn_s_sleep(16);
      if (__builtin_amdgcn_s_memrealtime() - t0 > (1ull << 25)) break;
    }
  }
  __syncthreads();
  __threadfence();
}

// ---- slot-wait: wave 0 polls all 32 slots (sc0 sc1 -> coherence point).
__device__ __forceinline__ void slot_wait(unsigned int* sg, unsigned target, int lane) {
  const unsigned int* myslot = sg + (size_t)(lane & 31) * 16;
  unsigned long long t0 = __builtin_amdgcn_s_memrealtime();
  for (;;) {
    unsigned v;
    asm volatile("global_load_dword %0, %1, off sc0 sc1\n\t"
                 "s_waitcnt vmcnt(0)"
                 : "=v"(v) : "v"(myslot) : "memory");
    if (__all(v >= target)) break;
    __builtin_amdgcn_s_sleep(1);
    if (__builtin_amdgcn_s_memrealtime() - t0 > (1ull << 23)) break;  // bail, never hang
  }
}

// ---- full slot barrier (r7/r8-proven): atomic arrival + sc0 sc1 poll.
__device__ __forceinline__ void xbar2(unsigned int* sg, int w, unsigned target,
                                      int wave, int lane) {
  asm volatile("s_waitcnt vmcnt(0)" ::: "memory");
  __syncthreads();
  if (wave == 0) {
    if (lane == 0)
      __hip_atomic_fetch_add(sg + (size_t)w * 16, 1u, __ATOMIC_RELAXED,
                             __HIP_MEMORY_SCOPE_AGENT);
    slot_wait(sg, target, lane);
  }
  __syncthreads();
}

__global__ __launch_bounds__(256, 1) void decoder_persistent(Params p) {
  __shared__ unsigned short w2l[BROW * W2S];    // 66 KB: W2 col-slice bf16
  __shared__ unsigned short albuf[BROW * AS];   // 66 KB: normalized A tile bf16
  __shared__ float g1l[NH], be1l[NH], g2l[NH], be2l[NH];  // 16 KB
  __shared__ unsigned short t1l[BROW * 40];     // 2.5 KB
  __shared__ unsigned short wa2l[16 * 40];      // 1.25 KB
  __shared__ float pj_l[BROW * NJ], pdq_l[BROW * NJ];
  __shared__ float alpha_l[NJ], jm_l[NJ], jri_l[NJ], lo_l[NJ], hi_l[NJ], ddp_l[NJ], ba2_l[NJ];
  __shared__ float pm_l[NPD], psi_l[NPD], bv_l[NPD], bo_l[4];

  const int tid = threadIdx.x;
  const int bid = blockIdx.x;
  const int g = bid & 7;
  const int w = bid >> 3;
  const int b0 = g * BROW;
  const int n0 = w * 32;
  const int wave = tid >> 6;
  const int lane = tid & 63;

  unsigned int* sg = p.slots + (size_t)g * 512;
  unsigned short* y1bg = p.y1b + (size_t)g * BROW * NH;
  unsigned short* y2bg = p.y2b + (size_t)g * BROW * NH;
  float* pa_gg = p.pa + (size_t)g * BROW * NJ * 32;
  float* part1g = p.part1 + (size_t)g * BROW * 64;    // [32 rows][32 w][2]
  float* part2g = p.part2 + (size_t)g * BROW * 128;   // [32 rows][32 w][2 ct][2]

  // ---------------- P0: one-time setup ----------------
  if (tid < NJ) {
    alpha_l[tid] = 1.f / (1.f + expf(-p.alog[tid]));
    float lo = p.jlo[tid], hi = p.jhi[tid];
    jm_l[tid] = 0.5f * (hi + lo);
    jri_l[tid] = 2.f / (hi - lo);
    lo_l[tid] = lo; hi_l[tid] = hi;
    ddp_l[tid] = p.ddp[tid]; ba2_l[tid] = p.ba2[tid];
  }
  if (tid < NPD) { pm_l[tid] = p.pmean[tid]; psi_l[tid] = 1.f / p.pstd[tid]; bv_l[tid] = p.bv[tid]; }
  if (tid < 3) bo_l[tid] = p.bo[tid];
  for (int idx = tid; idx < BROW * NJ; idx += 256) { pj_l[idx] = p.ddp[idx % NJ]; pdq_l[idx] = 0.f; }
  for (int idx = tid; idx < NH; idx += 256) {
    g1l[idx] = p.g1[idx]; be1l[idx] = p.be1[idx];
    g2l[idx] = p.g2[idx]; be2l[idx] = p.be2[idx];
  }
  for (int idx = tid; idx < BROW * NH; idx += 256) {
    int r = idx >> 10, k = idx & (NH - 1);
    w2l[r * W2S + k] = f2bf(p.W2[(size_t)(n0 + r) * NH + k]);
  }
  for (int idx = tid; idx < 16 * 32; idx += 256) {   // Wa2 slice -> LDS
    int rr = idx >> 5, cc = idx & 31;
    wa2l[rr * 40 + cc] = (rr < NJ) ? f2bf(p.Wa2[(size_t)rr * NH + n0 + cc]) : (unsigned short)0;
  }
  {  // zc = z @ W1z^T + b1 (constant across steps)
    int r = tid >> 3, cq = tid & 7;
    int nb = n0 + cq * 4;
    const float* zr = p.z + (size_t)(b0 + r) * 64;
    const float* w1r = p.W1 + (size_t)nb * NPIN + 75;
    float a0 = p.b1[nb], a1 = p.b1[nb + 1], a2 = p.b1[nb + 2], a3 = p.b1[nb + 3];
    for (int k = 0; k < 64; ++k) {
      float zv = zr[k];
      a0 += zv * w1r[k]; a1 += zv * w1r[NPIN + k];
      a2 += zv * w1r[2 * NPIN + k]; a3 += zv * w1r[3 * NPIN + k];
    }
    f32x4 st = {a0, a1, a2, a3};
    *(f32x4*)(p.zc + (size_t)(b0 + r) * NH + nb) = st;
  }
  for (int idx = tid; idx < 4 * NH; idx += 256) {  // Wa1 -> bf16 ws
    int r = idx >> 10, k = idx & (NH - 1);
    int row = n0 + g * 4 + r;
    p.wa1b[(size_t)row * NH + k] = f2bf(p.Wa1[(size_t)row * NH + k]);
  }
  if (bid == 1) {  // [Wo(3); Wv(42); zeros(3)] padded to 48 rows
    for (int idx = tid; idx < 48 * NH; idx += 256) {
      int r = idx >> 10, k = idx & (NH - 1);
      unsigned short v = 0;
      if (r < 3) v = f2bf(p.Wo[(size_t)r * NH + k]);
      else if (r < 45) v = f2bf(p.Wv[(size_t)(r - 3) * NH + k]);
      p.wexb[idx] = v;
    }
  }
  gbar(p.gcnt, 256u);

  // ---------------- phase lambdas ----------------
  auto stage_ln_apply = [&](const unsigned short* yg, const float* part, bool wide,
                            const float* gl, const float* bl) {
    const int r = tid >> 3, cq = tid & 7;
    const unsigned short* src = yg + (size_t)r * NH + cq * 8;
    unsigned short* dst = &albuf[r * AS + cq * 8];
    short8 v[16];
#pragma unroll
    for (int i = 0; i < 16; ++i) ld16_sc0(src + (size_t)i * 64, v[i]);
    const int fpr = wide ? 128 : 64;
    const float* pp = part + (size_t)r * fpr + cq * (fpr >> 3);
    f32x4 p0, p1, p2 = {0, 0, 0, 0}, p3 = {0, 0, 0, 0};
    ldf4_sc0(pp, p0);
    ldf4_sc0(pp + 4, p1);
    if (wide) { ldf4_sc0(pp + 8, p2); ldf4_sc0(pp + 12, p3); }
    vwait0();
    float s = p0[0] + p0[2] + p1[0] + p1[2];
    float q = p0[1] + p0[3] + p1[1] + p1[3];
    if (wide) {
      s += p2[0] + p2[2] + p3[0] + p3[2];
      q += p2[1] + p2[3] + p3[1] + p3[3];
    }
#pragma unroll
    for (int off = 4; off; off >>= 1) {
      s += __shfl_down(s, off, 8);
      q += __shfl_down(q, off, 8);
    }
    s = __shfl(s, 0, 8); q = __shfl(q, 0, 8);
    float m = s * (1.f / 1024.f);
    float rs = rsqrtf(q * (1.f / 1024.f) - m * m + 1e-5f);
    float nmrs = -m * rs;
#pragma unroll
    for (int i = 0; i < 16; ++i) {
      int c = cq * 8 + i * 64;
      f32x4 ga = *(const f32x4*)(gl + c);
      f32x4 gb = *(const f32x4*)(gl + c + 4);
      f32x4 ba = *(const f32x4*)(bl + c);
      f32x4 bb = *(const f32x4*)(bl + c + 4);
      float xn[8];
#pragma unroll
      for (int jj = 0; jj < 8; ++jj) {
        float x = bf2f((unsigned short)v[i][jj]);
        float tn = fmaf(x, rs, nmrs);
        float gg = (jj < 4) ? ga[jj] : gb[jj - 4];
        float bv2 = (jj < 4) ? ba[jj] : bb[jj - 4];
        xn[jj] = fmaxf(fmaf(tn, gg, bv2), 0.f);
      }
      uint4 pk = {cvt_pk_bf16(xn[0], xn[1]), cvt_pk_bf16(xn[2], xn[3]),
                  cvt_pk_bf16(xn[4], xn[5]), cvt_pk_bf16(xn[6], xn[7])};
      *(uint4*)(dst + i * 64) = pk;
    }
  };

  // P1 split: obs-part (state-independent) / finish (state-dependent).
  auto P1_obs = [&](int t) -> f32x4 {
    int r = tid >> 3, cq = tid & 7;
    int nb = n0 + cq * 4;
    f32x4 acc = *(const f32x4*)(p.zc + (size_t)(b0 + r) * NH + nb);
    const float* w1r = p.W1 + (size_t)nb * NPIN;
    const float* ob = p.obs + ((size_t)(b0 + r) * NS + t) * 51;
    for (int o = 0; o < 51; ++o) {
      float ov = ob[o];
      acc[0] += ov * w1r[24 + o]; acc[1] += ov * w1r[NPIN + 24 + o];
      acc[2] += ov * w1r[2 * NPIN + 24 + o]; acc[3] += ov * w1r[3 * NPIN + 24 + o];
    }
    return acc;
  };
  auto P1_fin = [&](f32x4 acc) {
    int r = tid >> 3, cq = tid & 7;
    int nb = n0 + cq * 4;
    float xj[24];
#pragma unroll
    for (int j = 0; j < NJ; ++j) {
      xj[j] = (pj_l[r * NJ + j] - jm_l[j]) * jri_l[j];
      xj[12 + j] = pdq_l[r * NJ + j];
    }
    const float* w1r = p.W1 + (size_t)nb * NPIN;
#pragma unroll
    for (int k = 0; k < 24; ++k) {
      float xv = xj[k];
      acc[0] += xv * w1r[k]; acc[1] += xv * w1r[NPIN + k];
      acc[2] += xv * w1r[2 * NPIN + k]; acc[3] += xv * w1r[3 * NPIN + k];
    }
    u16x4 hv = {f2bf(acc[0]), f2bf(acc[1]), f2bf(acc[2]), f2bf(acc[3])};
    *(u16x4*)(y1bg + (size_t)r * NH + nb) = hv;
    float s = acc[0] + acc[1] + acc[2] + acc[3];
    float q = acc[0] * acc[0] + acc[1] * acc[1] + acc[2] * acc[2] + acc[3] * acc[3];
#pragma unroll
    for (int off = 4; off; off >>= 1) {
      s += __shfl_down(s, off, 8);
      q += __shfl_down(q, off, 8);
    }
    if ((tid & 7) == 0) {
      float* pw = part1g + (size_t)r * 64 + w * 2;
      pw[0] = s; pw[1] = q;
    }
  };

  auto Yphase = [&]() {  // h1 = relu(LN1(y1)); y2 = h1 @ W2^T + b2 + LN2 partials
    stage_ln_apply(y1bg, part1g, false, g1l, be1l);
    __syncthreads();
    int rt = wave >> 1, ct = wave & 1;
    int kq = (lane >> 4) * 8;
    const unsigned short* a = &albuf[(rt * 16 + (lane & 15)) * AS + kq];
    const unsigned short* b = &w2l[(ct * 16 + (lane & 15)) * W2S + kq];
    f32x4 acc = dot1024(a, b);
    int col = n0 + ct * 16 + (lane & 15);
    float b2v = p.b2[col];
    float sv[4], qv[4];
#pragma unroll
    for (int i = 0; i < 4; ++i) {
      int row = rt * 16 + (lane >> 4) * 4 + i;
      float val = acc[i] + b2v;
      y2bg[(size_t)row * NH + col] = f2bf(val);
      sv[i] = val; qv[i] = val * val;
    }
#pragma unroll
    for (int mask = 1; mask < 16; mask <<= 1) {
#pragma unroll
      for (int i = 0; i < 4; ++i) {
        sv[i] += __shfl_xor(sv[i], mask, 64);
        qv[i] += __shfl_xor(qv[i], mask, 64);
      }
    }
    if ((lane & 15) == 0) {
      int rbase = rt * 16 + (lane >> 4) * 4;
#pragma unroll
      for (int i = 0; i < 4; ++i) {
        float* pw = part2g + (size_t)(rbase + i) * 128 + (w * 2 + ct) * 2;
        pw[0] = sv[i]; pw[1] = qv[i];
      }
    }
  };

  auto Zphase = [&](int t) {  // h = relu(LN2(y2)); t1 -> LDS; pa partials; heads
    stage_ln_apply(y2bg, part2g, true, g2l, be2l);
    __syncthreads();
    int rt = wave >> 1, ct = wave & 1;
    int kq = (lane >> 4) * 8;
    {
      const unsigned short* a = &albuf[(rt * 16 + (lane & 15)) * AS + kq];
      const unsigned short* b = p.wa1b + (size_t)(n0 + ct * 16 + (lane & 15)) * NH + kq;
      f32x4 acc = dot1024(a, b);
      int lcol = ct * 16 + (lane & 15);
      float bav = p.ba1[n0 + lcol];
#pragma unroll
      for (int i = 0; i < 4; ++i) {
        int row = rt * 16 + (lane >> 4) * 4 + i;
        t1l[row * 40 + lcol] = f2bf(fmaxf(acc[i] + bav, 0.f));
      }
    }
    __syncthreads();
    if (wave < 2) {  // pa[32 rows][12 j] partial over this WG's 32 cols
      int k0 = (lane >> 4) * 8;
      short8 a8 = *(const short8*)&t1l[(wave * 16 + (lane & 15)) * 40 + k0];
      short8 b8 = *(const short8*)&wa2l[(lane & 15) * 40 + k0];
      f32x4 z4 = {0.f, 0.f, 0.f, 0.f};
      f32x4 d = __builtin_amdgcn_mfma_f32_16x16x32_bf16(a8, b8, z4, 0, 0, 0);
      int j = lane & 15;
      if (j < NJ) {
#pragma unroll
        for (int i = 0; i < 4; ++i) {
          int row = wave * 16 + (lane >> 4) * 4 + i;
          pa_gg[((size_t)row * NJ + j) * 32 + w] = d[i];
        }
      }
    }
    if (w >= 26 && wave == 3) {  // heads: [Wo|Wv] 6 extra 16x16 tiles off albuf
      int e = w - 26, cte = e >> 1, rte = e & 1;
      const unsigned short* a = &albuf[(rte * 16 + (lane & 15)) * AS + kq];
      const unsigned short* b = p.wexb + (size_t)(cte * 16 + (lane & 15)) * NH + kq;
      f32x4 acc = dot1024(a, b);
      int ec = cte * 16 + (lane & 15);
#pragma unroll
      for (int i = 0; i < 4; ++i) {
        int row = rte * 16 + (lane >> 4) * 4 + i;
        int bb = b0 + row;
        if (ec < 3) {
          float val = acc[i] + bo_l[ec];
          p.out_gmu[((size_t)bb * NS + t) * NPD + 39 + ec] = (val - pm_l[39 + ec]) * psi_l[39 + ec];
        } else if (ec < 45) {
          int sv2 = ec - 3;
          float val = acc[i] + bv_l[sv2];
          float sig = 0.05f + 0.45f / (1.f + expf(-val));
          p.out_ls[((size_t)bb * NS + t) * NPD + sv2] = logf(sig);
        }
      }
    }
  };

  auto Xmid = [&](int tp) {  // reduce pa -> a; state update; outputs for step tp
    for (int e = tid; e < BROW * NJ; e += 256) {
      const float* pp = pa_gg + (size_t)e * 32;
      f32x4 u[8];
#pragma unroll
      for (int c2 = 0; c2 < 8; ++c2) ldf4_sc0(pp + c2 * 4, u[c2]);
      vwait0();
      f32x4 ss = ((u[0] + u[1]) + (u[2] + u[3])) + ((u[4] + u[5]) + (u[6] + u[7]));
      float sum = ss[0] + ss[1] + ss[2] + ss[3];
      int r = e / NJ, j = e - r * NJ;
      float av = tanhf(sum + ba2_l[j]);
      float pj = pj_l[e];
      float tgt = av * 0.25f + ddp_l[j];
      float cj = pj + alpha_l[j] * (tgt - pj);
      cj = fminf(fmaxf(cj, lo_l[j]), hi_l[j]);
      pdq_l[e] = (cj - pj) * 30.f;
      pj_l[e] = cj;
      if (w == 0) {
        size_t o = ((size_t)(b0 + r) * NS + tp) * NJ + j;
        p.out_joint[o] = cj;
        p.out_act[o] = av;
      }
    }
    __syncthreads();
    if (w == 0) {  // agent FK + normalize -> graph_x_mu[:, :, 0:39]
      for (int idx = tid; idx < BROW * 39; idx += 256) {
        int r = idx / 39, m = idx - r * 39;
        float s = p.fkb[m];
        const float* fw = p.fkW + m * NJ;
#pragma unroll
        for (int j = 0; j < NJ; ++j) s += pj_l[r * NJ + j] * fw[j];
        p.out_gmu[((size_t)(b0 + r) * NS + tp) * NPD + m] = (s - pm_l[m]) * psi_l[m];
      }
    }
  };

  // ---------------- step loop ----------------
  unsigned nbar = 0;
  {  // prologue: t = 0
    f32x4 acc = P1_obs(0);
    P1_fin(acc);
    xbar2(sg, w, ++nbar, wave, lane);   // A: y1(0) + part1 complete
  }
  for (int t = 0; t < NS; ++t) {
    Yphase();
    xbar2(sg, w, ++nbar, wave, lane);   // B: y2 + part2 complete
    Zphase(t);
    // ---- split-phase barrier C: arrive, overlap obs-dot, wait ----
    unsigned tc = ++nbar;
    asm volatile("s_waitcnt vmcnt(0)" ::: "memory");
    __syncthreads();
    if (tid == 0)
      __hip_atomic_fetch_add(sg + (size_t)w * 16, 1u, __ATOMIC_RELAXED,
                             __HIP_MEMORY_SCOPE_AGENT);
    f32x4 acc = {0.f, 0.f, 0.f, 0.f};
    if (t + 1 < NS) acc = P1_obs(t + 1);   // state-independent, overlaps C settle
    if (wave == 0) slot_wait(sg, tc, lane);
    __syncthreads();                       // C: pa + heads complete
    Xmid(t);                               // state update (internal syncthreads)
    if (t + 1 < NS) {
      P1_fin(acc);                         // uses fresh pj/pdq
      xbar2(sg, w, ++nbar, wave, lane);    // A: y1(t+1) + part1 complete
    }
  }
}

extern "C" void kernel_launch(void* const* d_in, const int* in_sizes, int n_in,
                              void* d_out, int out_size, void* d_ws, size_t ws_size,
                              hipStream_t stream) {
  (void)in_sizes; (void)n_in; (void)out_size; (void)ws_size;
  char* ws = (char*)d_ws;
  Params p;
  p.z = (const float*)d_in[0];   p.obs = (const float*)d_in[1];
  p.W1 = (const float*)d_in[2];  p.b1 = (const float*)d_in[3];
  p.g1 = (const float*)d_in[4];  p.be1 = (const float*)d_in[5];
  p.W2 = (const float*)d_in[6];  p.b2 = (const float*)d_in[7];
  p.g2 = (const float*)d_in[8];  p.be2 = (const float*)d_in[9];
  p.Wa1 = (const float*)d_in[10]; p.ba1 = (const float*)d_in[11];
  p.Wa2 = (const float*)d_in[12]; p.ba2 = (const float*)d_in[13];
  p.Wo = (const float*)d_in[14]; p.bo = (const float*)d_in[15];
  p.Wv = (const float*)d_in[16]; p.bv = (const float*)d_in[17];
  p.alog = (const float*)d_in[18];
  p.fkW = (const float*)d_in[19]; p.fkb = (const float*)d_in[20];
  p.pmean = (const float*)d_in[21]; p.pstd = (const float*)d_in[22];
  p.jlo = (const float*)d_in[23]; p.jhi = (const float*)d_in[24];
  p.ddp = (const float*)d_in[25];

  float* out = (float*)d_out;
  p.out_gmu = out;                                 // [256,128,42]
  p.out_joint = out + (size_t)256 * 128 * 42;      // [256,128,12]
  p.out_act = p.out_joint + (size_t)256 * 128 * 12;
  p.out_ls = p.out_act + (size_t)256 * 128 * 12;   // [256,128,42]

  p.gcnt = (unsigned int*)(ws + 0);
  p.slots = (unsigned int*)(ws + 1024);            // 8 x 32 x 64B = 16KB
  size_t off = (size_t)1 << 15;
  p.zc = (float*)(ws + off);                 off += (size_t)NB * NH * 4;          // 1MB
  p.y1b = (unsigned short*)(ws + off);       off += (size_t)NB * NH * 2;          // 512KB
  p.y2b = (unsigned short*)(ws + off);       off += (size_t)NB * NH * 2;          // 512KB
  p.pa = (float*)(ws + off);                 off += (size_t)8 * 32 * 12 * 32 * 4; // 384KB
  p.part1 = (float*)(ws + off);              off += (size_t)8 * 32 * 64 * 4;      // 64KB
  p.part2 = (float*)(ws + off);              off += (size_t)8 * 32 * 128 * 4;     // 128KB
  p.wa1b = (unsigned short*)(ws + off);      off += (size_t)NH * NH * 2;          // 2MB
  p.wexb = (unsigned short*)(ws + off);

  // counters/slots must start at 0 each call (monotonic within a call)
  hipMemsetAsync(d_ws, 0, 1 << 15, stream);
  decoder_persistent<<<dim3(256), dim3(256), 0, stream>>>(p);
}